// Round 7
// baseline (162.230 us; speedup 1.0000x reference)
//
#include <hip/hip_runtime.h>
#include <stdint.h>

#define D_EMB 100
#define NSYM 100001           // NUM_SYMBOLS + 1 rows in symbol_emb
#define BATCH 2048
#define NNEI 200
#define P_STRIDE 304          // fp8 P row stride in BYTES (8-B aligned rows)
#define FP8_SCALE 256.0f
#define FP8_INV   0.00390625f // 1/256
#define PL 5056               // padded plane stride in dwords (79 chunks x 64)

#define BP_ELEMS   32000      // packed Bp: 20 tiles x (3ks x 4q x 16n x 8 + 16n x 4)
#define BP_KS3_OFF 30720      // start of the dense ks=3 region

typedef __bf16 bf16x8 __attribute__((ext_vector_type(8)));
typedef __bf16 bf16x4 __attribute__((ext_vector_type(4)));
typedef float  f32x4  __attribute__((ext_vector_type(4)));
typedef float  f32x2  __attribute__((ext_vector_type(2)));

// async global->LDS DMA, 4 B per lane, dest = uniform base + lane*4
__device__ __forceinline__ void async_ld4(const void* g, void* l) {
    __builtin_amdgcn_global_load_lds(
        (const __attribute__((address_space(1))) uint32_t*)g,
        (__attribute__((address_space(3))) uint32_t*)l, 4, 0, 0);
}

// col covered by (tile tau, A-row n): paired-tile permutation so that
// lane quad's acc(tile 2u) ++ acc(tile 2u+1) = 8 consecutive P-columns.
__host__ __device__ inline int colmap(int tau, int n) {
    return 32 * (tau >> 1) + 8 * (n >> 2) + 4 * (tau & 1) + (n & 3);
}

// ---------------------------------------------------------------------------
// Kernel 1: repack gcn_w (100 x 300 fp32) into packed fragment-ordered Bp.
// ---------------------------------------------------------------------------
__global__ __launch_bounds__(256) void prep_bp(const float* __restrict__ gcn_w,
                                               __bf16* __restrict__ Bp) {
    int idx = blockIdx.x * 256 + threadIdx.x;
    if (idx >= BP_ELEMS) return;
    int tau, n, k;
    if (idx < BP_KS3_OFF) {
        int j = idx & 7;
        n     = (idx >> 3) & 15;
        int z = idx >> 7;            // tau*12 + ks*4 + q
        tau   = z / 12;
        int r = z - tau * 12;
        int ks = r >> 2, q = r & 3;
        k = ks * 32 + q * 8 + j;
    } else {
        int i2 = idx - BP_KS3_OFF;
        int j  = i2 & 3;
        n      = (i2 >> 2) & 15;
        tau    = i2 >> 6;
        k      = 96 + j;
    }
    const int col = colmap(tau, n);
    float v = 0.0f;
    if (col < 300 && k < 100) {
        int c = col / 100, d = col % 100;
        v = gcn_w[d * 300 + c * 100 + k];
    }
    Bp[idx] = (__bf16)v;
}

// ---------------------------------------------------------------------------
// helper: load one symbol row's emb fragment (B operand, K=128 w/ pad)
// ---------------------------------------------------------------------------
__device__ inline void load_bfrag(const float* __restrict__ rowp, int quad,
                                  bf16x8 b[4]) {
    #pragma unroll
    for (int ks = 0; ks < 3; ++ks) {                     // k0 <= 88
        const int k0 = ks * 32 + quad * 8;
        const float4 x = *(const float4*)(rowp + k0);
        const float4 y = *(const float4*)(rowp + k0 + 4);
        bf16x8 v;
        v[0]=(__bf16)x.x; v[1]=(__bf16)x.y; v[2]=(__bf16)x.z; v[3]=(__bf16)x.w;
        v[4]=(__bf16)y.x; v[5]=(__bf16)y.y; v[6]=(__bf16)y.z; v[7]=(__bf16)y.w;
        b[ks] = v;
    }
    bf16x8 v;
    #pragma unroll
    for (int i = 0; i < 8; ++i) v[i] = (__bf16)0.0f;
    if (quad == 0) {
        const float4 x = *(const float4*)(rowp + 96);
        v[0]=(__bf16)x.x; v[1]=(__bf16)x.y; v[2]=(__bf16)x.z; v[3]=(__bf16)x.w;
    }
    b[3] = v;
}

__device__ inline uint32_t pack_fp8x4(float a, float b, float c, float d) {
    uint32_t w = (uint32_t)__builtin_amdgcn_cvt_pk_fp8_f32(a, b, 0, false);
    w = (uint32_t)__builtin_amdgcn_cvt_pk_fp8_f32(c, d, (int)w, true);
    return w;
}

// ---------------------------------------------------------------------------
// Kernel 2: P8 = fp8_e4m3( symbol_emb @ W'^T * 256 ) -> (100001 x 304B).
// (unchanged from R5)
// ---------------------------------------------------------------------------
__global__ __launch_bounds__(512, 4) void gemm_P(const float* __restrict__ emb,
                                                 const __bf16* __restrict__ Bp,
                                                 uint8_t* __restrict__ P8) {
    __shared__ __bf16 BpS[BP_ELEMS + 8];     // + 8-elem zero slot

    const int tid  = threadIdx.x;
    const int wave = tid >> 6;               // 0..7
    const int lane = tid & 63;
    const int n    = lane & 15;
    const int quad = lane >> 4;

    {   // stage packed Bp into LDS (64,000 B contiguous, coalesced)
        const uint4* __restrict__ src = (const uint4*)Bp;
        uint4* dst = (uint4*)BpS;
        for (int c = tid; c < BP_ELEMS / 8; c += 512)    // 4000 x 16 B
            dst[c] = src[c];
        if (tid < 8) BpS[BP_ELEMS + tid] = (__bf16)0.0f; // zero slot
    }

    const int sA = blockIdx.x * 256 + wave * 32 + n;     // sym-tile A
    const int sB = sA + 16;                              // sym-tile B
    const int rA = (sA <= NSYM - 1) ? sA : (NSYM - 1);
    const int rB = (sB <= NSYM - 1) ? sB : (NSYM - 1);

    bf16x8 bA[4], bB[4];
    load_bfrag(emb + (size_t)rA * D_EMB, quad, bA);
    load_bfrag(emb + (size_t)rB * D_EMB, quad, bB);

    __syncthreads();

    const bool wrA = (sA <= NSYM - 1);
    const bool wrB = (sB <= NSYM - 1);
    uint8_t* __restrict__ prA = P8 + (size_t)sA * P_STRIDE;
    uint8_t* __restrict__ prB = P8 + (size_t)sB * P_STRIDE;

    for (int u = 0; u < 10; ++u) {
        const int t0 = 2 * u, t1 = t0 + 1;

        bf16x8 a0[4], a1[4];
        #pragma unroll
        for (int ks = 0; ks < 3; ++ks) {
            a0[ks] = *(const bf16x8*)&BpS[((t0 * 12 + ks * 4 + quad) * 16 + n) * 8];
            a1[ks] = *(const bf16x8*)&BpS[((t1 * 12 + ks * 4 + quad) * 16 + n) * 8];
        }
        {   // ks = 3: quad 0 reads dense 4-elem chunk; others read zero slot
            const int o0 = (quad == 0) ? (BP_KS3_OFF + (t0 * 16 + n) * 4) : BP_ELEMS;
            const int o1 = (quad == 0) ? (BP_KS3_OFF + (t1 * 16 + n) * 4) : BP_ELEMS;
            const bf16x4 w0 = *(const bf16x4*)&BpS[o0];
            const bf16x4 w1 = *(const bf16x4*)&BpS[o1];
            bf16x8 v0, v1;
            #pragma unroll
            for (int i = 0; i < 4; ++i) {
                v0[i] = w0[i]; v1[i] = w1[i];
                v0[i + 4] = (__bf16)0.0f; v1[i + 4] = (__bf16)0.0f;
            }
            a0[3] = v0; a1[3] = v1;
        }

        f32x4 aA0 = {0.f,0.f,0.f,0.f}, aA1 = {0.f,0.f,0.f,0.f};
        f32x4 aB0 = {0.f,0.f,0.f,0.f}, aB1 = {0.f,0.f,0.f,0.f};
        #pragma unroll
        for (int ks = 0; ks < 4; ++ks) {
            aA0 = __builtin_amdgcn_mfma_f32_16x16x32_bf16(a0[ks], bA[ks], aA0, 0, 0, 0);
            aA1 = __builtin_amdgcn_mfma_f32_16x16x32_bf16(a1[ks], bA[ks], aA1, 0, 0, 0);
            aB0 = __builtin_amdgcn_mfma_f32_16x16x32_bf16(a0[ks], bB[ks], aB0, 0, 0, 0);
            aB1 = __builtin_amdgcn_mfma_f32_16x16x32_bf16(a1[ks], bB[ks], aB1, 0, 0, 0);
        }

        const int colBase = 32 * u + 8 * quad;
        if (colBase + 8 <= 300) {
            if (wrA) {
                uint2 o;
                o.x = pack_fp8x4(aA0[0]*FP8_SCALE, aA0[1]*FP8_SCALE,
                                 aA0[2]*FP8_SCALE, aA0[3]*FP8_SCALE);
                o.y = pack_fp8x4(aA1[0]*FP8_SCALE, aA1[1]*FP8_SCALE,
                                 aA1[2]*FP8_SCALE, aA1[3]*FP8_SCALE);
                *(uint2*)(prA + colBase) = o;
            }
            if (wrB) {
                uint2 o;
                o.x = pack_fp8x4(aB0[0]*FP8_SCALE, aB0[1]*FP8_SCALE,
                                 aB0[2]*FP8_SCALE, aB0[3]*FP8_SCALE);
                o.y = pack_fp8x4(aB1[0]*FP8_SCALE, aB1[1]*FP8_SCALE,
                                 aB1[2]*FP8_SCALE, aB1[3]*FP8_SCALE);
                *(uint2*)(prB + colBase) = o;
            }
        } else if (colBase + 4 <= 300) {                 // u=9, q=1: 296..299
            if (wrA)
                *(uint32_t*)(prA + colBase) =
                    pack_fp8x4(aA0[0]*FP8_SCALE, aA0[1]*FP8_SCALE,
                               aA0[2]*FP8_SCALE, aA0[3]*FP8_SCALE);
            if (wrB)
                *(uint32_t*)(prB + colBase) =
                    pack_fp8x4(aB0[0]*FP8_SCALE, aB0[1]*FP8_SCALE,
                               aB0[2]*FP8_SCALE, aB0[3]*FP8_SCALE);
        }
    }
}

// ---------------------------------------------------------------------------
// Kernel 3: per-batch fused gather + attention + gate.
// Phase A: fire-and-forget global_load_lds DMA of all 15,000 fp8 dwords
// (3 planes x 200 n x 25 dwords) — no VGPR round-trip, max MLP.
// Phase B: logits from planes (dequant on the fly, 5 thr/neighbor).
// Softmax; Phase C: weighted sum from planes (dequant again — bit-identical);
// gate; blend with self-embedding.
// ---------------------------------------------------------------------------
__global__ __launch_bounds__(1024, 8) void gather_attn(
        const int*     __restrict__ conn,        // (2048, 200, 4) int32
        const uint8_t* __restrict__ P8,          // (100001, 304B) fp8 e4m3
        const float*   __restrict__ emb,         // (100001, 100) fp32
        const float*   __restrict__ gcn_w_bias,
        const float*   __restrict__ gcn_b,
        const float*   __restrict__ attn_w,      // (100,)
        const float*   __restrict__ attn_bias,   // (1,)
        const float*   __restrict__ gate_w,      // (100,)
        const float*   __restrict__ gate_w_bias, // (1,)
        const float*   __restrict__ gate_b,      // (1,)
        float* __restrict__ out) {

    __shared__ uint32_t planes[3 * PL];        // 60,672 B raw fp8 dwords
    __shared__ int4   conn_s[NNEI];            //  3,200 B
    __shared__ float  logit5[NNEI][5];         //  4,000 B
    __shared__ float  logits[NNEI];
    __shared__ float  wgt[NNEI];
    __shared__ float4 aw4_s[25];
    __shared__ float4 bias4_s[25];
    __shared__ float  part[16][D_EMB];         //  6,400 B
    __shared__ float  red[128];
    __shared__ float  gsh;

    const int b = blockIdx.x;
    const int t = threadIdx.x;
    const int w = t >> 6;
    const int l = t & 63;

    if (t < NNEI) conn_s[t] = *(const int4*)(conn + ((size_t)b * NNEI + t) * 4);
    if (t < 25) {
        aw4_s[t]   = *(const float4*)(attn_w + 4 * t);
        bias4_s[t] = make_float4(gcn_w_bias[4*t]   + gcn_b[4*t],
                                 gcn_w_bias[4*t+1] + gcn_b[4*t+1],
                                 gcn_w_bias[4*t+2] + gcn_b[4*t+2],
                                 gcn_w_bias[4*t+3] + gcn_b[4*t+3]);
    }
    const float abias = attn_bias[0];
    __syncthreads();

    // ---- Phase A: DMA. 79 chunks x 64 lanes covers 5000 items + pad. ----
    for (int c = w; c < 79; c += 16) {
        const int item = c * 64 + l;
        int n = item / 25;
        const int li = item - n * 25;
        n = (n < NNEI) ? n : (NNEI - 1);       // pad lanes -> safe dummy
        const int4 ci = conn_s[n];
        const uint8_t* g0 = P8 + (size_t)ci.y * P_STRIDE +       li * 4;
        const uint8_t* g1 = P8 + (size_t)ci.z * P_STRIDE + 100 + li * 4;
        const uint8_t* g2 = P8 + (size_t)ci.w * P_STRIDE + 200 + li * 4;
        async_ld4(g0, &planes[0 * PL + c * 64]);
        async_ld4(g1, &planes[1 * PL + c * 64]);
        async_ld4(g2, &planes[2 * PL + c * 64]);
    }
    __syncthreads();                            // drains vmcnt

    // ---- Phase B: logits. 5 threads per neighbor, 5 dwords each. ----
    if (t < 5 * NNEI) {
        const int n = t / 5, q = t - (t / 5) * 5;
        float p = 0.f;
        #pragma unroll
        for (int j = 5 * q; j < 5 * q + 5; ++j) {
            const uint32_t u0 = planes[0 * PL + n * 25 + j];
            const uint32_t u1 = planes[1 * PL + n * 25 + j];
            const uint32_t u2 = planes[2 * PL + n * 25 + j];
            const f32x2 y0 = __builtin_amdgcn_cvt_pk_f32_fp8((int)u0, false);
            const f32x2 y1 = __builtin_amdgcn_cvt_pk_f32_fp8((int)u0, true);
            const f32x2 z0 = __builtin_amdgcn_cvt_pk_f32_fp8((int)u1, false);
            const f32x2 z1 = __builtin_amdgcn_cvt_pk_f32_fp8((int)u1, true);
            const f32x2 q0 = __builtin_amdgcn_cvt_pk_f32_fp8((int)u2, false);
            const f32x2 q1 = __builtin_amdgcn_cvt_pk_f32_fp8((int)u2, true);
            const float4 bb = bias4_s[j];
            const float4 aw = aw4_s[j];
            float v0 = (y0[0] + z0[0] + q0[0]) * FP8_INV + bb.x;
            float v1 = (y0[1] + z0[1] + q0[1]) * FP8_INV + bb.y;
            float v2 = (y1[0] + z1[0] + q1[0]) * FP8_INV + bb.z;
            float v3 = (y1[1] + z1[1] + q1[1]) * FP8_INV + bb.w;
            v0 = fmaxf(v0, 0.01f * v0);
            v1 = fmaxf(v1, 0.01f * v1);
            v2 = fmaxf(v2, 0.01f * v2);
            v3 = fmaxf(v3, 0.01f * v3);
            p += v0 * aw.x + v1 * aw.y + v2 * aw.z + v3 * aw.w;
        }
        logit5[n][q] = p;
    }
    __syncthreads();

    if (t < NNEI)
        logits[t] = logit5[t][0] + logit5[t][1] + logit5[t][2]
                  + logit5[t][3] + logit5[t][4] + abias;
    __syncthreads();

    // ---- softmax over all 200 neighbors (wave 0) ----
    if (w == 0) {
        float vals[4];
        float mx = -1e30f;
        #pragma unroll
        for (int j = 0; j < 4; ++j) {
            const int n = l + 64 * j;
            vals[j] = (n < NNEI) ? logits[n] : -1e30f;
            mx = fmaxf(mx, vals[j]);
        }
        #pragma unroll
        for (int off = 32; off > 0; off >>= 1) mx = fmaxf(mx, __shfl_xor(mx, off));
        float sum = 0.f;
        #pragma unroll
        for (int j = 0; j < 4; ++j) {
            const int n = l + 64 * j;
            if (n < NNEI) { const float e = __expf(vals[j] - mx); wgt[n] = e; sum += e; }
        }
        #pragma unroll
        for (int off = 32; off > 0; off >>= 1) sum += __shfl_xor(sum, off);
        const float inv = 1.f / sum;
        #pragma unroll
        for (int j = 0; j < 4; ++j) {
            const int n = l + 64 * j;
            if (n < NNEI) wgt[n] *= inv;
        }
    }
    __syncthreads();

    // ---- Phase C: weighted sum. thread (li, g, h): dims 4li..4li+3,
    //      neighbors g*25 + [h?12:0 .. h?25:12) ----
    if (t < 400) {
        const int li = t % 25;
        const int z  = t / 25;                 // 0..15
        const int g  = z >> 1, h = z & 1;
        const int n0 = g * 25 + (h ? 12 : 0);
        const int n1 = g * 25 + (h ? 25 : 12);
        const float4 bb = bias4_s[li];
        float s0 = 0.f, s1 = 0.f, s2 = 0.f, s3 = 0.f;
        for (int n = n0; n < n1; ++n) {
            const float wn = wgt[n];
            const uint32_t u0 = planes[0 * PL + n * 25 + li];
            const uint32_t u1 = planes[1 * PL + n * 25 + li];
            const uint32_t u2 = planes[2 * PL + n * 25 + li];
            const f32x2 y0 = __builtin_amdgcn_cvt_pk_f32_fp8((int)u0, false);
            const f32x2 y1 = __builtin_amdgcn_cvt_pk_f32_fp8((int)u0, true);
            const f32x2 z0 = __builtin_amdgcn_cvt_pk_f32_fp8((int)u1, false);
            const f32x2 z1 = __builtin_amdgcn_cvt_pk_f32_fp8((int)u1, true);
            const f32x2 q0 = __builtin_amdgcn_cvt_pk_f32_fp8((int)u2, false);
            const f32x2 q1 = __builtin_amdgcn_cvt_pk_f32_fp8((int)u2, true);
            float v0 = (y0[0] + z0[0] + q0[0]) * FP8_INV + bb.x;
            float v1 = (y0[1] + z0[1] + q0[1]) * FP8_INV + bb.y;
            float v2 = (y1[0] + z1[0] + q1[0]) * FP8_INV + bb.z;
            float v3 = (y1[1] + z1[1] + q1[1]) * FP8_INV + bb.w;
            v0 = fmaxf(v0, 0.01f * v0);
            v1 = fmaxf(v1, 0.01f * v1);
            v2 = fmaxf(v2, 0.01f * v2);
            v3 = fmaxf(v3, 0.01f * v3);
            s0 += wn * v0; s1 += wn * v1; s2 += wn * v2; s3 += wn * v3;
        }
        *(float4*)&part[z][4 * li] = make_float4(s0, s1, s2, s3);
    }
    __syncthreads();

    float accd = 0.f;
    if (t < D_EMB) {
        #pragma unroll
        for (int z = 0; z < 16; ++z) accd += part[z][t];
        red[t] = accd * gate_w[t];
    } else if (t < 128) {
        red[t] = 0.f;
    }
    __syncthreads();

    if (w == 0) {
        float r = red[l] + red[l + 64];
        #pragma unroll
        for (int off = 32; off > 0; off >>= 1) r += __shfl_xor(r, off);
        if (l == 0) gsh = 1.f / (1.f + __expf(-(r + gate_w_bias[0] + gate_b[0])));
    }
    __syncthreads();

    if (t < D_EMB) {
        const int self = conn_s[0].x;              // connections[b][0][0]
        const float se = emb[(size_t)self * D_EMB + t];
        const float g  = gsh;
        out[(size_t)b * D_EMB + t] = accd * g + se * (1.f - g);
    }
}

// Diagnostic: if workspace is too small, encode ws_size (in MB) in d_out[0].
__global__ void ws_diag(float* out, float ws_mb) { out[0] = ws_mb; }

extern "C" void kernel_launch(void* const* d_in, const int* in_sizes, int n_in,
                              void* d_out, int out_size, void* d_ws, size_t ws_size,
                              hipStream_t stream) {
    const int*   conn        = (const int*)d_in[0];
    // d_in[1] = num_neighbors — unused by the reference
    const float* emb         = (const float*)d_in[2];
    const float* gcn_w       = (const float*)d_in[3];
    const float* gcn_w_bias  = (const float*)d_in[4];
    const float* gcn_b       = (const float*)d_in[5];
    const float* attn_w      = (const float*)d_in[6];
    const float* attn_bias   = (const float*)d_in[7];
    const float* gate_w      = (const float*)d_in[8];
    const float* gate_w_bias = (const float*)d_in[9];
    const float* gate_b      = (const float*)d_in[10];
    float* out = (float*)d_out;

    const size_t P_bytes = (size_t)NSYM * P_STRIDE;                // 30,400,304
    const size_t Bp_off  = (P_bytes + 255) & ~(size_t)255;
    const size_t need    = Bp_off + (size_t)BP_ELEMS * 2;          // +64,000

    if (ws_size < need) {
        ws_diag<<<1, 1, 0, stream>>>(out, (float)(ws_size / 1.0e6));
        return;
    }

    uint8_t* P8 = (uint8_t*)d_ws;
    __bf16*  Bp = (__bf16*)((char*)d_ws + Bp_off);

    prep_bp<<<(BP_ELEMS + 255) / 256, 256, 0, stream>>>(gcn_w, Bp);
    gemm_P<<<(NSYM + 255) / 256, 512, 0, stream>>>(emb, Bp, P8);
    gather_attn<<<BATCH, 1024, 0, stream>>>(conn, P8, emb, gcn_w_bias, gcn_b,
                                            attn_w, attn_bias, gate_w, gate_w_bias,
                                            gate_b, out);
}

// Round 8
// 149.479 us; speedup vs baseline: 1.0853x; 1.0853x over previous
//
#include <hip/hip_runtime.h>
#include <stdint.h>

#define D_EMB 100
#define NSYM 100001           // NUM_SYMBOLS + 1 rows in symbol_emb
#define BATCH 2048
#define NNEI 200
#define P_STRIDE 304          // fp8 P row stride in BYTES (8-B aligned rows)
#define FP8_SCALE 256.0f
#define FP8_INV   0.00390625f // 1/256

#define BP_ELEMS   32000      // packed Bp: 20 tiles x (3ks x 4q x 16n x 8 + 16n x 4)
#define BP_KS3_OFF 30720      // start of the dense ks=3 region

typedef __bf16 bf16x8 __attribute__((ext_vector_type(8)));
typedef __bf16 bf16x4 __attribute__((ext_vector_type(4)));
typedef float  f32x4  __attribute__((ext_vector_type(4)));
typedef float  f32x2  __attribute__((ext_vector_type(2)));

// col covered by (tile tau, A-row n): paired-tile permutation so that
// lane quad's acc(tile 2u) ++ acc(tile 2u+1) = 8 consecutive P-columns.
__host__ __device__ inline int colmap(int tau, int n) {
    return 32 * (tau >> 1) + 8 * (n >> 2) + 4 * (tau & 1) + (n & 3);
}

// ---------------------------------------------------------------------------
// Kernel 1: repack gcn_w (100 x 300 fp32) into packed fragment-ordered Bp.
// ---------------------------------------------------------------------------
__global__ __launch_bounds__(256) void prep_bp(const float* __restrict__ gcn_w,
                                               __bf16* __restrict__ Bp) {
    int idx = blockIdx.x * 256 + threadIdx.x;
    if (idx >= BP_ELEMS) return;
    int tau, n, k;
    if (idx < BP_KS3_OFF) {
        int j = idx & 7;
        n     = (idx >> 3) & 15;
        int z = idx >> 7;            // tau*12 + ks*4 + q
        tau   = z / 12;
        int r = z - tau * 12;
        int ks = r >> 2, q = r & 3;
        k = ks * 32 + q * 8 + j;
    } else {
        int i2 = idx - BP_KS3_OFF;
        int j  = i2 & 3;
        n      = (i2 >> 2) & 15;
        tau    = i2 >> 6;
        k      = 96 + j;
    }
    const int col = colmap(tau, n);
    float v = 0.0f;
    if (col < 300 && k < 100) {
        int c = col / 100, d = col % 100;
        v = gcn_w[d * 300 + c * 100 + k];
    }
    Bp[idx] = (__bf16)v;
}

// ---------------------------------------------------------------------------
// helper: load one symbol row's emb fragment (B operand, K=128 w/ pad)
// ---------------------------------------------------------------------------
__device__ inline void load_bfrag(const float* __restrict__ rowp, int quad,
                                  bf16x8 b[4]) {
    #pragma unroll
    for (int ks = 0; ks < 3; ++ks) {                     // k0 <= 88
        const int k0 = ks * 32 + quad * 8;
        const float4 x = *(const float4*)(rowp + k0);
        const float4 y = *(const float4*)(rowp + k0 + 4);
        bf16x8 v;
        v[0]=(__bf16)x.x; v[1]=(__bf16)x.y; v[2]=(__bf16)x.z; v[3]=(__bf16)x.w;
        v[4]=(__bf16)y.x; v[5]=(__bf16)y.y; v[6]=(__bf16)y.z; v[7]=(__bf16)y.w;
        b[ks] = v;
    }
    bf16x8 v;
    #pragma unroll
    for (int i = 0; i < 8; ++i) v[i] = (__bf16)0.0f;
    if (quad == 0) {
        const float4 x = *(const float4*)(rowp + 96);
        v[0]=(__bf16)x.x; v[1]=(__bf16)x.y; v[2]=(__bf16)x.z; v[3]=(__bf16)x.w;
    }
    b[3] = v;
}

__device__ inline uint32_t pack_fp8x4(float a, float b, float c, float d) {
    uint32_t w = (uint32_t)__builtin_amdgcn_cvt_pk_fp8_f32(a, b, 0, false);
    w = (uint32_t)__builtin_amdgcn_cvt_pk_fp8_f32(c, d, (int)w, true);
    return w;
}

// ---------------------------------------------------------------------------
// Kernel 2: P8 = fp8_e4m3( symbol_emb @ W'^T * 256 ) -> (100001 x 304B).
// (unchanged from R5)
// ---------------------------------------------------------------------------
__global__ __launch_bounds__(512, 4) void gemm_P(const float* __restrict__ emb,
                                                 const __bf16* __restrict__ Bp,
                                                 uint8_t* __restrict__ P8) {
    __shared__ __bf16 BpS[BP_ELEMS + 8];     // + 8-elem zero slot

    const int tid  = threadIdx.x;
    const int wave = tid >> 6;               // 0..7
    const int lane = tid & 63;
    const int n    = lane & 15;
    const int quad = lane >> 4;

    {   // stage packed Bp into LDS (64,000 B contiguous, coalesced)
        const uint4* __restrict__ src = (const uint4*)Bp;
        uint4* dst = (uint4*)BpS;
        for (int c = tid; c < BP_ELEMS / 8; c += 512)    // 4000 x 16 B
            dst[c] = src[c];
        if (tid < 8) BpS[BP_ELEMS + tid] = (__bf16)0.0f; // zero slot
    }

    const int sA = blockIdx.x * 256 + wave * 32 + n;     // sym-tile A
    const int sB = sA + 16;                              // sym-tile B
    const int rA = (sA <= NSYM - 1) ? sA : (NSYM - 1);
    const int rB = (sB <= NSYM - 1) ? sB : (NSYM - 1);

    bf16x8 bA[4], bB[4];
    load_bfrag(emb + (size_t)rA * D_EMB, quad, bA);
    load_bfrag(emb + (size_t)rB * D_EMB, quad, bB);

    __syncthreads();

    const bool wrA = (sA <= NSYM - 1);
    const bool wrB = (sB <= NSYM - 1);
    uint8_t* __restrict__ prA = P8 + (size_t)sA * P_STRIDE;
    uint8_t* __restrict__ prB = P8 + (size_t)sB * P_STRIDE;

    for (int u = 0; u < 10; ++u) {
        const int t0 = 2 * u, t1 = t0 + 1;

        bf16x8 a0[4], a1[4];
        #pragma unroll
        for (int ks = 0; ks < 3; ++ks) {
            a0[ks] = *(const bf16x8*)&BpS[((t0 * 12 + ks * 4 + quad) * 16 + n) * 8];
            a1[ks] = *(const bf16x8*)&BpS[((t1 * 12 + ks * 4 + quad) * 16 + n) * 8];
        }
        {   // ks = 3: quad 0 reads dense 4-elem chunk; others read zero slot
            const int o0 = (quad == 0) ? (BP_KS3_OFF + (t0 * 16 + n) * 4) : BP_ELEMS;
            const int o1 = (quad == 0) ? (BP_KS3_OFF + (t1 * 16 + n) * 4) : BP_ELEMS;
            const bf16x4 w0 = *(const bf16x4*)&BpS[o0];
            const bf16x4 w1 = *(const bf16x4*)&BpS[o1];
            bf16x8 v0, v1;
            #pragma unroll
            for (int i = 0; i < 4; ++i) {
                v0[i] = w0[i]; v1[i] = w1[i];
                v0[i + 4] = (__bf16)0.0f; v1[i + 4] = (__bf16)0.0f;
            }
            a0[3] = v0; a1[3] = v1;
        }

        f32x4 aA0 = {0.f,0.f,0.f,0.f}, aA1 = {0.f,0.f,0.f,0.f};
        f32x4 aB0 = {0.f,0.f,0.f,0.f}, aB1 = {0.f,0.f,0.f,0.f};
        #pragma unroll
        for (int ks = 0; ks < 4; ++ks) {
            aA0 = __builtin_amdgcn_mfma_f32_16x16x32_bf16(a0[ks], bA[ks], aA0, 0, 0, 0);
            aA1 = __builtin_amdgcn_mfma_f32_16x16x32_bf16(a1[ks], bA[ks], aA1, 0, 0, 0);
            aB0 = __builtin_amdgcn_mfma_f32_16x16x32_bf16(a0[ks], bB[ks], aB0, 0, 0, 0);
            aB1 = __builtin_amdgcn_mfma_f32_16x16x32_bf16(a1[ks], bB[ks], aB1, 0, 0, 0);
        }

        const int colBase = 32 * u + 8 * quad;
        if (colBase + 8 <= 300) {
            if (wrA) {
                uint2 o;
                o.x = pack_fp8x4(aA0[0]*FP8_SCALE, aA0[1]*FP8_SCALE,
                                 aA0[2]*FP8_SCALE, aA0[3]*FP8_SCALE);
                o.y = pack_fp8x4(aA1[0]*FP8_SCALE, aA1[1]*FP8_SCALE,
                                 aA1[2]*FP8_SCALE, aA1[3]*FP8_SCALE);
                *(uint2*)(prA + colBase) = o;
            }
            if (wrB) {
                uint2 o;
                o.x = pack_fp8x4(aB0[0]*FP8_SCALE, aB0[1]*FP8_SCALE,
                                 aB0[2]*FP8_SCALE, aB0[3]*FP8_SCALE);
                o.y = pack_fp8x4(aB1[0]*FP8_SCALE, aB1[1]*FP8_SCALE,
                                 aB1[2]*FP8_SCALE, aB1[3]*FP8_SCALE);
                *(uint2*)(prB + colBase) = o;
            }
        } else if (colBase + 4 <= 300) {                 // u=9, q=1: 296..299
            if (wrA)
                *(uint32_t*)(prA + colBase) =
                    pack_fp8x4(aA0[0]*FP8_SCALE, aA0[1]*FP8_SCALE,
                               aA0[2]*FP8_SCALE, aA0[3]*FP8_SCALE);
            if (wrB)
                *(uint32_t*)(prB + colBase) =
                    pack_fp8x4(aB0[0]*FP8_SCALE, aB0[1]*FP8_SCALE,
                               aB0[2]*FP8_SCALE, aB0[3]*FP8_SCALE);
        }
    }
}

// ---------------------------------------------------------------------------
// Kernel 3: per-batch fused gather + attention + gate.
// 512 thr (8 waves) per batch row, ~36 KB LDS -> 4 blocks/CU co-resident
// (32 waves/CU + 4-deep cross-block phase overlap). v is stored in LDS as
// fp8 e4m3 dwords in the x256-scaled domain (leaky-relu commutes with
// positive scale); 1/256 applied once at logits and final reduction.
// ---------------------------------------------------------------------------
__global__ __launch_bounds__(512, 8) void gather_attn(
        const int*     __restrict__ conn,        // (2048, 200, 4) int32
        const uint8_t* __restrict__ P8,          // (100001, 304B) fp8 e4m3
        const float*   __restrict__ emb,         // (100001, 100) fp32
        const float*   __restrict__ gcn_w_bias,
        const float*   __restrict__ gcn_b,
        const float*   __restrict__ attn_w,      // (100,)
        const float*   __restrict__ attn_bias,   // (1,)
        const float*   __restrict__ gate_w,      // (100,)
        const float*   __restrict__ gate_w_bias, // (1,)
        const float*   __restrict__ gate_b,      // (1,)
        float* __restrict__ out) {

    __shared__ uint32_t vs[NNEI * 25];         // 20,000 B  scaled-fp8 v
    __shared__ int4     conn_s[NNEI];          //  3,200 B
    __shared__ float    logit2[NNEI][2];       //  1,600 B
    __shared__ float    logits[NNEI];          //    800 B
    __shared__ float    wgt[NNEI];             //    800 B
    __shared__ float4   aw4_s[25];             //    400 B
    __shared__ float4   bias4_s[25];           //    400 B  (x256 domain)
    __shared__ float    part[20][D_EMB];       //  8,000 B  (scaled domain)
    __shared__ float    red[128];
    __shared__ float    gsh;

    const int b = blockIdx.x;
    const int t = threadIdx.x;
    const int w = t >> 6;
    const int l = t & 63;

    if (t < NNEI) conn_s[t] = *(const int4*)(conn + ((size_t)b * NNEI + t) * 4);
    if (t < 25) {
        aw4_s[t]   = *(const float4*)(attn_w + 4 * t);
        bias4_s[t] = make_float4((gcn_w_bias[4*t]   + gcn_b[4*t])   * FP8_SCALE,
                                 (gcn_w_bias[4*t+1] + gcn_b[4*t+1]) * FP8_SCALE,
                                 (gcn_w_bias[4*t+2] + gcn_b[4*t+2]) * FP8_SCALE,
                                 (gcn_w_bias[4*t+3] + gcn_b[4*t+3]) * FP8_SCALE);
    }
    const float abias = attn_bias[0];
    __syncthreads();

    // ---- Phase 1: gather. 5000 items = (n, li); 2 halves x 5 batched loads.
    #pragma unroll
    for (int half = 0; half < 2; ++half) {
        uint32_t U[5][3];
        #pragma unroll
        for (int j = 0; j < 5; ++j) {
            const int idx = t + 512 * (5 * half + j);
            if (idx < NNEI * 25) {
                const int n  = idx / 25;
                const int li = idx - n * 25;
                const int4 c = conn_s[n];
                U[j][0] = *(const uint32_t*)(P8 + (size_t)c.y * P_STRIDE +       li * 4);
                U[j][1] = *(const uint32_t*)(P8 + (size_t)c.z * P_STRIDE + 100 + li * 4);
                U[j][2] = *(const uint32_t*)(P8 + (size_t)c.w * P_STRIDE + 200 + li * 4);
            }
        }
        #pragma unroll
        for (int j = 0; j < 5; ++j) {
            const int idx = t + 512 * (5 * half + j);
            if (idx < NNEI * 25) {
                const int li = idx % 25;
                const f32x2 y0 = __builtin_amdgcn_cvt_pk_f32_fp8((int)U[j][0], false);
                const f32x2 y1 = __builtin_amdgcn_cvt_pk_f32_fp8((int)U[j][0], true);
                const f32x2 z0 = __builtin_amdgcn_cvt_pk_f32_fp8((int)U[j][1], false);
                const f32x2 z1 = __builtin_amdgcn_cvt_pk_f32_fp8((int)U[j][1], true);
                const f32x2 q0 = __builtin_amdgcn_cvt_pk_f32_fp8((int)U[j][2], false);
                const f32x2 q1 = __builtin_amdgcn_cvt_pk_f32_fp8((int)U[j][2], true);
                const float4 bb = bias4_s[li];
                float v0 = y0[0] + z0[0] + q0[0] + bb.x;   // x256 domain
                float v1 = y0[1] + z0[1] + q0[1] + bb.y;
                float v2 = y1[0] + z1[0] + q1[0] + bb.z;
                float v3 = y1[1] + z1[1] + q1[1] + bb.w;
                v0 = fmaxf(v0, 0.01f * v0);                // scale-invariant
                v1 = fmaxf(v1, 0.01f * v1);
                v2 = fmaxf(v2, 0.01f * v2);
                v3 = fmaxf(v3, 0.01f * v3);
                vs[idx] = pack_fp8x4(v0, v1, v2, v3);
            }
        }
    }
    __syncthreads();

    // ---- Phase B: logits. 2 threads per neighbor (13 + 12 dwords). ----
    if (t < 2 * NNEI) {
        const int n = t >> 1, h = t & 1;
        const int lo = h ? 13 : 0, hi = h ? 25 : 13;
        float p = 0.f;                                      // x256 domain
        for (int j = lo; j < hi; ++j) {
            const uint32_t u = vs[n * 25 + j];
            const f32x2 a = __builtin_amdgcn_cvt_pk_f32_fp8((int)u, false);
            const f32x2 c = __builtin_amdgcn_cvt_pk_f32_fp8((int)u, true);
            const float4 aw = aw4_s[j];
            p += a[0] * aw.x + a[1] * aw.y + c[0] * aw.z + c[1] * aw.w;
        }
        logit2[n][h] = p;
    }
    __syncthreads();
    if (t < NNEI)
        logits[t] = (logit2[t][0] + logit2[t][1]) * FP8_INV + abias;
    __syncthreads();

    // ---- softmax over all 200 neighbors (wave 0) ----
    if (w == 0) {
        float vals[4];
        float mx = -1e30f;
        #pragma unroll
        for (int j = 0; j < 4; ++j) {
            const int n = l + 64 * j;
            vals[j] = (n < NNEI) ? logits[n] : -1e30f;
            mx = fmaxf(mx, vals[j]);
        }
        #pragma unroll
        for (int off = 32; off > 0; off >>= 1) mx = fmaxf(mx, __shfl_xor(mx, off));
        float sum = 0.f;
        #pragma unroll
        for (int j = 0; j < 4; ++j) {
            const int n = l + 64 * j;
            if (n < NNEI) { const float e = __expf(vals[j] - mx); wgt[n] = e; sum += e; }
        }
        #pragma unroll
        for (int off = 32; off > 0; off >>= 1) sum += __shfl_xor(sum, off);
        const float inv = 1.f / sum;
        #pragma unroll
        for (int j = 0; j < 4; ++j) {
            const int n = l + 64 * j;
            if (n < NNEI) wgt[n] *= inv;
        }
    }
    __syncthreads();

    // ---- Phase C: weighted sum. thread (z, li): z = n-range (10 each),
    //      li = 4-dim chunk. Column reads vs[n*25+li]: stride 25, gcd(25,32)=1
    //      -> conflict-free. ----
    if (t < 500) {
        const int z  = t / 25;                 // 0..19
        const int li = t - z * 25;
        const int n0 = z * 10;
        float s0 = 0.f, s1 = 0.f, s2 = 0.f, s3 = 0.f;   // x256 domain
        #pragma unroll 5
        for (int n = n0; n < n0 + 10; ++n) {
            const float wn = wgt[n];
            const uint32_t u = vs[n * 25 + li];
            const f32x2 a = __builtin_amdgcn_cvt_pk_f32_fp8((int)u, false);
            const f32x2 c = __builtin_amdgcn_cvt_pk_f32_fp8((int)u, true);
            s0 += wn * a[0]; s1 += wn * a[1]; s2 += wn * c[0]; s3 += wn * c[1];
        }
        *(float4*)&part[z][4 * li] = make_float4(s0, s1, s2, s3);
    }
    __syncthreads();

    float accd = 0.f;
    if (t < D_EMB) {
        #pragma unroll
        for (int z = 0; z < 20; ++z) accd += part[z][t];
        accd *= FP8_INV;                       // back to real scale
        red[t] = accd * gate_w[t];
    } else if (t < 128) {
        red[t] = 0.f;
    }
    __syncthreads();

    if (w == 0) {
        float r = red[l] + red[l + 64];
        #pragma unroll
        for (int off = 32; off > 0; off >>= 1) r += __shfl_xor(r, off);
        if (l == 0) gsh = 1.f / (1.f + __expf(-(r + gate_w_bias[0] + gate_b[0])));
    }
    __syncthreads();

    if (t < D_EMB) {
        const int self = conn_s[0].x;              // connections[b][0][0]
        const float se = emb[(size_t)self * D_EMB + t];
        const float g  = gsh;
        out[(size_t)b * D_EMB + t] = accd * g + se * (1.f - g);
    }
}

// Diagnostic: if workspace is too small, encode ws_size (in MB) in d_out[0].
__global__ void ws_diag(float* out, float ws_mb) { out[0] = ws_mb; }

extern "C" void kernel_launch(void* const* d_in, const int* in_sizes, int n_in,
                              void* d_out, int out_size, void* d_ws, size_t ws_size,
                              hipStream_t stream) {
    const int*   conn        = (const int*)d_in[0];
    // d_in[1] = num_neighbors — unused by the reference
    const float* emb         = (const float*)d_in[2];
    const float* gcn_w       = (const float*)d_in[3];
    const float* gcn_w_bias  = (const float*)d_in[4];
    const float* gcn_b       = (const float*)d_in[5];
    const float* attn_w      = (const float*)d_in[6];
    const float* attn_bias   = (const float*)d_in[7];
    const float* gate_w      = (const float*)d_in[8];
    const float* gate_w_bias = (const float*)d_in[9];
    const float* gate_b      = (const float*)d_in[10];
    float* out = (float*)d_out;

    const size_t P_bytes = (size_t)NSYM * P_STRIDE;                // 30,400,304
    const size_t Bp_off  = (P_bytes + 255) & ~(size_t)255;
    const size_t need    = Bp_off + (size_t)BP_ELEMS * 2;          // +64,000

    if (ws_size < need) {
        ws_diag<<<1, 1, 0, stream>>>(out, (float)(ws_size / 1.0e6));
        return;
    }

    uint8_t* P8 = (uint8_t*)d_ws;
    __bf16*  Bp = (__bf16*)((char*)d_ws + Bp_off);

    prep_bp<<<(BP_ELEMS + 255) / 256, 256, 0, stream>>>(gcn_w, Bp);
    gemm_P<<<(NSYM + 255) / 256, 512, 0, stream>>>(emb, Bp, P8);
    gather_attn<<<BATCH, 512, 0, stream>>>(conn, P8, emb, gcn_w_bias, gcn_b,
                                           attn_w, attn_bias, gate_w, gate_w_bias,
                                           gate_b, out);
}